// Round 1
// baseline (600.515 us; speedup 1.0000x reference)
//
#include <hip/hip_runtime.h>
#include <math.h>

// NSLoss: N=16384 pairs, D=128, NUM_SAMPLED=10, weights table 1e6 x 128 f32.
// loss = -(1/N) * sum_i [ log_sigmoid(<emb_i, W[label_i]>)
//                         + sum_k log_sigmoid(-<emb_i, W[negs_ik]>) ]
//
// One wave (64 lanes) per pair: lane l holds float2 of the 128-wide row
// (one coalesced 512B load per row). 11 weight-row gathers issued up front
// for latency overlap, then butterfly shuffle reductions. Block partial via
// LDS, one atomicAdd per block.

#define NPAIRS 16384
#define DIM 128
#define NSAMP 10

__device__ __forceinline__ float log_sigmoid(float x) {
    // stable: min(x,0) - log1p(exp(-|x|))
    return fminf(x, 0.0f) - log1pf(__expf(-fabsf(x)));
}

__global__ __launch_bounds__(256) void nsloss_kernel(
    const float* __restrict__ emb,      // [N, 128]
    const float* __restrict__ weights,  // [1e6, 128]
    const int*   __restrict__ label,    // [N]
    const int*   __restrict__ negs,     // [N, 10]
    float* __restrict__ out)            // [1]
{
    const int wave = threadIdx.x >> 6;        // 0..3
    const int lane = threadIdx.x & 63;
    const int i = (blockIdx.x << 2) + wave;   // pair index, grid = N/4 exact

    // emb row fragment: lane l -> elements 2l, 2l+1  (coalesced dwordx2)
    const float2 e = *(const float2*)(emb + (size_t)i * DIM + 2 * lane);

    // gather the 11 row indices (scalar, broadcast via cache)
    int idx[NSAMP + 1];
    idx[0] = label[i];
#pragma unroll
    for (int k = 0; k < NSAMP; ++k) idx[k + 1] = negs[i * NSAMP + k];

    // issue all 11 row loads before any reduction (latency overlap)
    float2 w[NSAMP + 1];
#pragma unroll
    for (int k = 0; k < NSAMP + 1; ++k)
        w[k] = *(const float2*)(weights + (size_t)idx[k] * DIM + 2 * lane);

    float loss = 0.0f;
#pragma unroll
    for (int k = 0; k < NSAMP + 1; ++k) {
        float s = e.x * w[k].x + e.y * w[k].y;
#pragma unroll
        for (int off = 32; off >= 1; off >>= 1)
            s += __shfl_xor(s, off, 64);
        loss += log_sigmoid(k == 0 ? s : -s);
    }

    __shared__ float part[4];
    if (lane == 0) part[wave] = loss;
    __syncthreads();
    if (threadIdx.x == 0) {
        float b = (part[0] + part[1]) + (part[2] + part[3]);
        atomicAdd(out, b * (-1.0f / (float)NPAIRS));
    }
}

extern "C" void kernel_launch(void* const* d_in, const int* in_sizes, int n_in,
                              void* d_out, int out_size, void* d_ws, size_t ws_size,
                              hipStream_t stream) {
    // inputs (setup_inputs order): y_hat[N] (unused), emb[N*128], weights[1e6*128],
    // label[N] (int), negs[N*10] (int)
    const float* emb     = (const float*)d_in[1];
    const float* weights = (const float*)d_in[2];
    const int*   label   = (const int*)d_in[3];
    const int*   negs    = (const int*)d_in[4];
    float* out = (float*)d_out;

    // d_out is re-poisoned to 0xAA before every replay — zero it in-graph.
    hipMemsetAsync(out, 0, sizeof(float), stream);

    nsloss_kernel<<<NPAIRS / 4, 256, 0, stream>>>(emb, weights, label, negs, out);
}

// Round 2
// 581.756 us; speedup vs baseline: 1.0322x; 1.0322x over previous
//
#include <hip/hip_runtime.h>
#include <math.h>

// NSLoss: N=16384 pairs, D=128, NUM_SAMPLED=10, weights table 1e6 x 128 f32.
// loss = -(1/N) * sum_i [ log_sigmoid(<emb_i, W[label_i]>)
//                         + sum_k log_sigmoid(-<emb_i, W[negs_ik]>) ]
//
// Stage 1: one wave (64 lanes) per pair; lane l holds float2 of the 128-wide
// row (one coalesced 512B load per row). 11 weight-row gathers issued up
// front for latency overlap, butterfly shuffle reductions, one partial per
// block written to d_ws (NO atomics — 4096 same-address atomicAdds across
// 8 XCDs serialized in R1).
// Stage 2: single block sums the 4096 partials and writes -sum/N to out[0]
// (removes the d_out memset dispatch too).

#define NPAIRS 16384
#define DIM 128
#define NSAMP 10
#define NBLOCKS (NPAIRS / 4)   // 4096

__device__ __forceinline__ float log_sigmoid(float x) {
    // stable: min(x,0) - log1p(exp(-|x|))
    return fminf(x, 0.0f) - log1pf(__expf(-fabsf(x)));
}

__global__ __launch_bounds__(256) void nsloss_partial_kernel(
    const float* __restrict__ emb,      // [N, 128]
    const float* __restrict__ weights,  // [1e6, 128]
    const int*   __restrict__ label,    // [N]
    const int*   __restrict__ negs,     // [N, 10]
    float* __restrict__ partials)       // [NBLOCKS]
{
    const int wave = threadIdx.x >> 6;        // 0..3
    const int lane = threadIdx.x & 63;
    const int i = (blockIdx.x << 2) + wave;   // pair index, grid = N/4 exact

    // emb row fragment: lane l -> elements 2l, 2l+1  (coalesced dwordx2)
    const float2 e = *(const float2*)(emb + (size_t)i * DIM + 2 * lane);

    // gather the 11 row indices (wave-uniform, scalarized by compiler)
    int idx[NSAMP + 1];
    idx[0] = label[i];
#pragma unroll
    for (int k = 0; k < NSAMP; ++k) idx[k + 1] = negs[i * NSAMP + k];

    // issue all 11 row loads before any reduction (latency overlap)
    float2 w[NSAMP + 1];
#pragma unroll
    for (int k = 0; k < NSAMP + 1; ++k)
        w[k] = *(const float2*)(weights + (size_t)idx[k] * DIM + 2 * lane);

    float loss = 0.0f;
#pragma unroll
    for (int k = 0; k < NSAMP + 1; ++k) {
        float s = e.x * w[k].x + e.y * w[k].y;
#pragma unroll
        for (int off = 32; off >= 1; off >>= 1)
            s += __shfl_xor(s, off, 64);
        loss += log_sigmoid(k == 0 ? s : -s);
    }

    __shared__ float part[4];
    if (lane == 0) part[wave] = loss;
    __syncthreads();
    if (threadIdx.x == 0)
        partials[blockIdx.x] = (part[0] + part[1]) + (part[2] + part[3]);
}

__global__ __launch_bounds__(256) void nsloss_reduce_kernel(
    const float* __restrict__ partials,  // [NBLOCKS]
    float* __restrict__ out)             // [1]
{
    const int t = threadIdx.x;
    float s = 0.0f;
#pragma unroll
    for (int j = 0; j < NBLOCKS / 256; ++j)   // 16 coalesced passes
        s += partials[j * 256 + t];
#pragma unroll
    for (int off = 32; off >= 1; off >>= 1)
        s += __shfl_xor(s, off, 64);

    __shared__ float part[4];
    if ((t & 63) == 0) part[t >> 6] = s;
    __syncthreads();
    if (t == 0)
        out[0] = ((part[0] + part[1]) + (part[2] + part[3])) * (-1.0f / (float)NPAIRS);
}

extern "C" void kernel_launch(void* const* d_in, const int* in_sizes, int n_in,
                              void* d_out, int out_size, void* d_ws, size_t ws_size,
                              hipStream_t stream) {
    // inputs (setup_inputs order): y_hat[N] (unused), emb[N*128], weights[1e6*128],
    // label[N] (int), negs[N*10] (int)
    const float* emb     = (const float*)d_in[1];
    const float* weights = (const float*)d_in[2];
    const int*   label   = (const int*)d_in[3];
    const int*   negs    = (const int*)d_in[4];
    float* out      = (float*)d_out;
    float* partials = (float*)d_ws;   // 4096 floats, re-poisoned each replay (we overwrite all)

    nsloss_partial_kernel<<<NBLOCKS, 256, 0, stream>>>(emb, weights, label, negs, partials);
    nsloss_reduce_kernel<<<1, 256, 0, stream>>>(partials, out);
}